// Round 8
// baseline (3563.671 us; speedup 1.0000x reference)
//
#include <hip/hip_runtime.h>
#include <hip/hip_fp16.h>

// ---------------------------------------------------------------------------
// 2-layer bidirectional tanh RNN, B=32, T=512, E=256, H=512.
//   prep:  fp32->fp16 conversions (+ xs transpose, bias sums)
//   gemm:  pre[d][t*32+b][j] = X @ W_ih[d]^T + bias   (fp16 MFMA)
//   rnn:   512 sequential steps; 16 worker blocks/dir on ONE XCD each, each
//          owns a 32-wide j-slice of W_hh in VGPRs (R1 geometry, proven).
//
// ROUND 8 — remove the costs COMMON to all prior variants (2.7-3.2us/step
// invariant across scope/fan-in/protocol changes):
//   1. TAGGED u64 protocol (R1, best-measured) at AGENT scope: no flag
//      store, no pre-flag vmcnt(0) drain — readers re-gather until tags
//      match.  Correct under any store ordering.
//   2. NO __syncthreads IN THE LOOP: __syncthreads drains vmcnt(0) (m97),
//      dragging ~1000cy HBM output-store acks into the serial chain every
//      step (vmcnt is in-order FIFO, m135).  Replaced by raw
//      "s_waitcnt lgkmcnt(0); s_barrier" (LDS-only visibility) + As double
//      buffer.  HBM stores now never block the chain.
//   3. Outputs staged in LDS (lgkmcnt domain, invisible to vmcnt), flushed
//      every 8 steps -> flush ack ~1000cy amortized to ~125cy/step.
//   4. HEATERS: 224 surplus blocks run a capped dependent-FMA spin until a
//      done flag -> holds SMU clocks up during this latency-bound kernel
//      (theory: ~1% busy lets clocks sag ~2x; explains the 2.7us invariant).
// ---------------------------------------------------------------------------

#define T_ 512
#define B_ 32
#define E_ 256
#define H_ 512

using half8 = _Float16 __attribute__((ext_vector_type(8)));
using f32x4 = float __attribute__((ext_vector_type(4)));
typedef unsigned long long u64;
typedef unsigned int u32;

// workspace layout (bytes)
static constexpr size_t OFF_PRE   = 0;                         // f16 [2][16384][512]  32 MB
static constexpr size_t OFF_XH1   = 32ull << 20;               // f16 [16384][1024]    32 MB
static constexpr size_t OFF_X0H   = 64ull << 20;               // f16 [16384][256]      8 MB
static constexpr size_t OFF_W0H   = 72ull << 20;               // f16 [2][512][256]   0.5 MB
static constexpr size_t OFF_W1H   = OFF_W0H + (512ull << 10);  // f16 [2][512][1024]    2 MB
static constexpr size_t OFF_WHH   = OFF_W1H + (2ull << 20);    // f16 [2][2][512][512]  2 MB
static constexpr size_t OFF_BS    = OFF_WHH + (2ull << 20);    // f32 [2][2][512]       8 KB
static constexpr size_t OFF_HX    = OFF_BS + (8ull << 10);     // u64 [2 lay][2 dir][2 ph][32][256] 512 KB
static constexpr size_t OFF_CTL   = OFF_HX + (512ull << 10);   // u32 [2 lay][32]  256 B
static constexpr size_t ZERO_SIZE = (512ull << 10) + 1024;     // hx + ctl

// u64 element strides inside hx
static constexpr size_t HX_LAYER_STRIDE = 2 * 2 * 32 * 256;    // 32768 u64 per layer
static constexpr size_t HX_DIR_STRIDE   = 2 * 32 * 256;        // 16384 u64 per dir

__device__ __forceinline__ float fast_tanh(float x) {
    // tanh(x) = (e^2x - 1)/(e^2x + 1), clamped so e^2x can't overflow.
    float cx = fminf(fmaxf(x, -9.0f), 9.0f);
    float e2 = __expf(2.0f * cx);
    return (e2 - 1.0f) * __builtin_amdgcn_rcpf(e2 + 1.0f);
}

// LDS-only barrier: does NOT drain vmcnt (unlike __syncthreads), so in-flight
// HBM stores/loads keep flowing across it.  "memory" clobber pins compiler
// ordering of LDS ops; sched_barrier pins the scheduler.
__device__ __forceinline__ void lds_barrier() {
    __builtin_amdgcn_sched_barrier(0);
    asm volatile("s_waitcnt lgkmcnt(0)\n\ts_barrier" ::: "memory");
    __builtin_amdgcn_sched_barrier(0);
}

// ---------------------------------------------------------------------------
__global__ void prep_kernel(const float* __restrict__ xs,
                            const float* __restrict__ wih0,
                            const float* __restrict__ whh0,
                            const float* __restrict__ b0,
                            const float* __restrict__ wih1,
                            const float* __restrict__ whh1,
                            const float* __restrict__ b1,
                            _Float16* __restrict__ x0h,
                            _Float16* __restrict__ w0h,
                            _Float16* __restrict__ w1h,
                            _Float16* __restrict__ whh,
                            float* __restrict__ bsum)
{
    const int N0 = T_ * B_ * E_;
    const int N1 = 2 * H_ * E_;
    const int N2 = 2 * H_ * 2*H_;
    const int N3 = 2 * H_ * H_;
    const int total = N0 + N1 + N2 + 2 * N3 + 2048;
    for (int idx = blockIdx.x * blockDim.x + threadIdx.x; idx < total;
         idx += gridDim.x * blockDim.x) {
        int i = idx;
        if (i < N0) {
            int t = i >> 13;
            int r = i & 8191;
            int b = r >> 8;
            int e = r & 255;
            x0h[i] = (_Float16)xs[((size_t)(b << 9) + t) * 256 + e];
        } else if ((i -= N0) < N1) {
            w0h[i] = (_Float16)wih0[i];
        } else if ((i -= N1) < N2) {
            w1h[i] = (_Float16)wih1[i];
        } else if ((i -= N2) < N3) {
            whh[i] = (_Float16)whh0[i];
        } else if ((i -= N3) < N3) {
            whh[N3 + i] = (_Float16)whh1[i];
        } else {
            i -= N3;               // 0..2047: [layer][dir][512]
            int layer = i >> 10;
            int r = i & 1023;
            int d = r >> 9;
            int j = r & 511;
            const float* bb = layer ? b1 : b0;
            bsum[i] = bb[d * 1024 + j] + bb[d * 1024 + 512 + j];
        }
    }
}

// ---------------------------------------------------------------------------
__global__ __launch_bounds__(256, 2)
void gemm_kernel(const _Float16* __restrict__ X,
                 const _Float16* __restrict__ W,
                 const float* __restrict__ bias,
                 _Float16* __restrict__ out, int K)
{
    __shared__ _Float16 Ash[64][72];
    __shared__ _Float16 Bsh[64][72];
    const int m0 = blockIdx.x * 64, n0 = blockIdx.y * 64, d = blockIdx.z;
    const _Float16* Wd = W + (size_t)d * 512 * K;
    const int tid = threadIdx.x;
    const int l = tid & 63, w = tid >> 6;
    const int wm = w & 1, wn = w >> 1;
    const int lm = l & 15, q = l >> 4;
    f32x4 c[2][2] = {};
    for (int kk = 0; kk < K; kk += 64) {
        for (int ci = tid; ci < 512; ci += 256) {
            int row = ci >> 3, col = (ci & 7) * 8;
            *(half8*)&Ash[row][col] =
                *(const half8*)&X[(size_t)(m0 + row) * K + kk + col];
            *(half8*)&Bsh[row][col] =
                *(const half8*)&Wd[(size_t)(n0 + row) * K + kk + col];
        }
        __syncthreads();
        for (int kt = 0; kt < 2; ++kt) {
            const int kof = kt * 32 + q * 8;
            half8 a0 = *(const half8*)&Ash[wm * 32 + lm][kof];
            half8 a1 = *(const half8*)&Ash[wm * 32 + 16 + lm][kof];
            half8 b0f = *(const half8*)&Bsh[wn * 32 + lm][kof];
            half8 b1f = *(const half8*)&Bsh[wn * 32 + 16 + lm][kof];
            c[0][0] = __builtin_amdgcn_mfma_f32_16x16x32_f16(a0, b0f, c[0][0], 0, 0, 0);
            c[0][1] = __builtin_amdgcn_mfma_f32_16x16x32_f16(a0, b1f, c[0][1], 0, 0, 0);
            c[1][0] = __builtin_amdgcn_mfma_f32_16x16x32_f16(a1, b0f, c[1][0], 0, 0, 0);
            c[1][1] = __builtin_amdgcn_mfma_f32_16x16x32_f16(a1, b1f, c[1][1], 0, 0, 0);
        }
        __syncthreads();
    }
    _Float16* outd = out + (size_t)d * 16384 * 512;
    for (int mi = 0; mi < 2; ++mi)
        for (int ni = 0; ni < 2; ++ni) {
            int col = n0 + wn * 32 + ni * 16 + lm;
            float bv = bias[d * 512 + col];
            for (int r = 0; r < 4; ++r) {
                int rowm = m0 + wm * 32 + mi * 16 + q * 4 + r;
                outd[(size_t)rowm * 512 + col] = (_Float16)(c[mi][ni][r] + bv);
            }
        }
}

// ---------------------------------------------------------------------------
// hx per dir: [2 phase][32 b][256 jp] u64; word = (tag<<32)|(f16 j=2jp+1)<<16|(f16 j=2jp)
// h(s) lives in phase s&1 with tag s (R1-proven protocol, agent scope).
// ctl per layer (u32[32]): [0..7] per-XCD claim counters, [8] rolecnt,
//   [16..23] xcdrole (0 unset, 1 dir0, 2 dir1, 3 none), [24] done flag.
__global__ __launch_bounds__(256)
void rnn_kernel(const _Float16* __restrict__ pre,   // [2][16384][512] f16
                const _Float16* __restrict__ whh,   // this layer: [2][512][512] f16
                u64* __restrict__ hx,               // this layer: [2 dir][2 ph][32][256] u64
                u32* __restrict__ ctl,              // this layer: [32] u32
                _Float16* __restrict__ xh1,         // layer0 out: [16384][1024] f16
                float* __restrict__ dout,           // final output buffer
                int layer)
{
    __shared__ uint4 As[2][64 * 33];                // A-frag staging, dbuf, 67.6 KB
    __shared__ float stF[8 * 32 * 36];              // 8-step output stage, 36.9 KB
    __shared__ int sh_role, sh_slot;

    const int tid = threadIdx.x;

    // ---- XCD-aware worker claiming (tid 0 only, broadcast via LDS) ----
    if (tid == 0) {
        int xcc;
        asm volatile("s_getreg_b32 %0, hwreg(HW_REG_XCC_ID)" : "=s"(xcc));
        xcc &= 7;
        u32 slot = __hip_atomic_fetch_add(&ctl[xcc], 1u, __ATOMIC_RELAXED,
                                          __HIP_MEMORY_SCOPE_SYSTEM);
        int role = 0;
        if (slot < 16u) {
            if (slot == 15u) {
                // 16th block on this XCD: group complete -> claim a role.
                u32 r = __hip_atomic_fetch_add(&ctl[8], 1u, __ATOMIC_ACQ_REL,
                                               __HIP_MEMORY_SCOPE_SYSTEM);
                role = (r < 2u) ? (int)r + 1 : 3;
                __hip_atomic_store(&ctl[16 + xcc], (u32)role, __ATOMIC_RELEASE,
                                   __HIP_MEMORY_SCOPE_SYSTEM);
            } else {
                long it = 0;
                while (true) {
                    u32 r = __hip_atomic_load(&ctl[16 + xcc], __ATOMIC_ACQUIRE,
                                              __HIP_MEMORY_SCOPE_SYSTEM);
                    if (r) { role = (int)r; break; }
                    if (++it > 100000000) { role = 3; break; }   // paranoia escape
                }
            }
        }
        sh_role = role;
        sh_slot = (int)slot;
    }
    __syncthreads();
    const int role = sh_role;
    const int g = sh_slot;                          // worker id within direction
    if (role == 0 || role == 3) {
        // ---- HEATER: hold SMU clocks up while workers run latency-bound.
        //      Two dependent FMA chains (~50% VALU issue); poll the done
        //      word (LLC, no worker-L2 pollution) every 16 outer iters.
        //      Hard cap ~3ms bounds runtime even if done were missed.
        float ha = 1.0f + (float)(tid & 31) * 1e-7f;
        float hc = 1.0f - (float)(tid & 7) * 1e-7f;
        for (int it = 0; it < 60000; ++it) {
#pragma unroll 32
            for (int u = 0; u < 32; ++u) {
                ha = __builtin_fmaf(ha, 0.99999988f, 1e-9f);
                hc = __builtin_fmaf(hc, 1.00000012f, -1e-9f);
            }
            if ((it & 15) == 0) {
                if (__hip_atomic_load(&ctl[24], __ATOMIC_RELAXED,
                                      __HIP_MEMORY_SCOPE_SYSTEM)) break;
            }
        }
        asm volatile("" :: "v"(ha), "v"(hc));       // keep chains live
        return;
    }
    const int d = role - 1;

    const int wv = tid >> 6, l = tid & 63;
    const int lm = l & 15, q = l >> 4;
    const int wm = wv & 1, wn = wv >> 1;
    const int jn = g * 32 + wn * 16;                // this wave's 16-col slice
    const int bA = wm * 16 + lm;                    // A-frag row (b)
    const int bq = wm * 16 + q * 4;                 // C/D row base (b)
    const int jl = wn * 16 + lm;                    // col within block's 32-slice

    // Preload W B-fragments: lane holds W[j = jn+lm][k = kt*32 + q*8 + e]
    half8 Bf[16];
    {
        const _Float16* wrow = whh + ((size_t)d * 512 + jn + lm) * 512;
#pragma unroll
        for (int kt = 0; kt < 16; ++kt)
            Bf[kt] = *(const half8*)&wrow[kt * 32 + q * 8];
    }

    u64* hbd = hx + (size_t)d * HX_DIR_STRIDE;      // [2 phase][32][256]
    const int jp_pub = (jn + (lm & ~1)) >> 1;       // word this lane-pair publishes
    const int scat_base = ((tid >> 2) * 33) * 4 + (tid & 3);  // LDS dword idx base (b=0)

    for (int s = 0; s < T_; ++s) {
        const int t = d ? (T_ - 1 - s) : s;

        // ---- issue pre loads (oldest in vmcnt FIFO: the gather's own wait
        //      retires them for free; consumed at acc init) ----
        const _Float16* prow = pre + ((size_t)d * 16384 + (size_t)t * B_) * 512 + jn + lm;
        _Float16 pv[4];
#pragma unroll
        for (int r = 0; r < 4; ++r)
            pv[r] = prow[(size_t)(bq + r) * 512];

        // ---- tagged poll-gather of h(s): lane tid <- [b=i][jp=tid] (R1) ----
        const u64* src = hbd + (size_t)(s & 1) * 8192 + tid;
        const unsigned tag = (unsigned)s;
        u64 wvv[32];
        {
            bool stale = true;
            long it = 0;
            do {
#pragma unroll
                for (int i = 0; i < 32; ++i)
                    wvv[i] = __hip_atomic_load(&src[i * 256],
                                               __ATOMIC_RELAXED, __HIP_MEMORY_SCOPE_AGENT);
                bool ok = true;
#pragma unroll
                for (int i = 0; i < 32; ++i)
                    ok &= ((unsigned)(wvv[i] >> 32) == tag);
                stale = __any(!ok);
            } while (stale && ++it < 2000000);      // escape => wrong data, not hang
        }

        // ---- LDS scatter to A-frag layout (dbuf) ----
        u32* AsW = (u32*)&As[s & 1][0];
#pragma unroll
        for (int i = 0; i < 32; ++i)
            AsW[scat_base + i * 4] = (u32)wvv[i];
        lds_barrier();                              // LDS-only: vmcnt untouched

        // ---- A-fragments + MFMA (two accumulator chains, R1) ----
        f32x4 c0, c1;
#pragma unroll
        for (int r = 0; r < 4; ++r) { c0[r] = (float)pv[r]; c1[r] = 0.0f; }
#pragma unroll
        for (int kt = 0; kt < 16; ++kt) {
            union { uint4 u; half8 h; } cv;
            cv.u = As[s & 1][(kt * 4 + q) * 33 + bA];
            if (kt & 1) c1 = __builtin_amdgcn_mfma_f32_16x16x32_f16(cv.h, Bf[kt], c1, 0, 0, 0);
            else        c0 = __builtin_amdgcn_mfma_f32_16x16x32_f16(cv.h, Bf[kt], c0, 0, 0, 0);
        }

        // ---- tanh + tagged publish (no drain, no flag; readers tag-check) ----
        u64* dst = hbd + (size_t)((s + 1) & 1) * 8192;
        const u64 tagw = ((u64)(unsigned)(s + 1)) << 32;
        const int j = jn + lm;
        float hv[4];
        unsigned hb[4];
#pragma unroll
        for (int r = 0; r < 4; ++r) {
            hv[r] = fast_tanh(c0[r] + c1[r]);
            union { _Float16 f; unsigned short u; } cb;
            cb.f = (_Float16)hv[r];
            hb[r] = cb.u;
        }
#pragma unroll
        for (int r = 0; r < 4; ++r) {
            unsigned p = __shfl_xor(hb[r], 1, 64);
            unsigned lo = (l & 1) ? p : hb[r];
            unsigned hi = (l & 1) ? hb[r] : p;
            if ((r >> 1) == (l & 1)) {   // even lane stores r=0,1; odd r=2,3
                u64 word = tagw | ((u64)hi << 16) | lo;
                __hip_atomic_store(&dst[(size_t)(bq + r) * 256 + jp_pub], word,
                                   __ATOMIC_RELAXED, __HIP_MEMORY_SCOPE_AGENT);
            }
        }

        // ---- outputs -> LDS stage (lgkmcnt domain; invisible to vmcnt) ----
#pragma unroll
        for (int r = 0; r < 4; ++r)
            stF[((s & 7) * 32 + (bq + r)) * 36 + jl] = hv[r];
        if (s == T_ - 1) {              // hy: once, direct
#pragma unroll
            for (int r = 0; r < 4; ++r)
                dout[16777216ull + ((size_t)(layer * 2 + d) * B_ + (bq + r)) * 512 + j] = hv[r];
        }

        // ---- flush staged outputs every 8 steps (acks amortize 8x) ----
        if ((s & 7) == 7) {
            lds_barrier();                          // all waves' stF writes visible
            const int sp = tid >> 5, b = tid & 31;
            const int ss = (s & ~7) | sp;
            const int tt = d ? (T_ - 1 - ss) : ss;
            const float* sf = &stF[(sp * 32 + b) * 36];
            if (layer == 0) {
                _Float16* dp = xh1 + ((size_t)tt * B_ + b) * 1024 + d * 512 + g * 32;
#pragma unroll
                for (int k = 0; k < 4; ++k) {
                    half8 h;
#pragma unroll
                    for (int e = 0; e < 8; ++e) h[e] = (_Float16)sf[k * 8 + e];
                    *(half8*)&dp[k * 8] = h;
                }
            } else {
                float* dp = dout + ((size_t)b * T_ + tt) * 1024 + d * 512 + g * 32;
#pragma unroll
                for (int k = 0; k < 8; ++k)
                    *(f32x4*)&dp[k * 4] = *(const f32x4*)&sf[k * 4];
            }
        }
    }

    // signal heaters to exit
    if (tid == 0)
        __hip_atomic_store(&ctl[24], 1u, __ATOMIC_RELAXED,
                           __HIP_MEMORY_SCOPE_SYSTEM);
}

// ---------------------------------------------------------------------------
extern "C" void kernel_launch(void* const* d_in, const int* in_sizes, int n_in,
                              void* d_out, int out_size, void* d_ws, size_t ws_size,
                              hipStream_t stream)
{
    const float* xs   = (const float*)d_in[0];
    const float* wih0 = (const float*)d_in[1];
    const float* whh0 = (const float*)d_in[2];
    const float* b0   = (const float*)d_in[3];
    const float* wih1 = (const float*)d_in[4];
    const float* whh1 = (const float*)d_in[5];
    const float* b1   = (const float*)d_in[6];

    char* ws = (char*)d_ws;
    _Float16* pre  = (_Float16*)(ws + OFF_PRE);
    _Float16* xh1  = (_Float16*)(ws + OFF_XH1);
    _Float16* x0h  = (_Float16*)(ws + OFF_X0H);
    _Float16* w0h  = (_Float16*)(ws + OFF_W0H);
    _Float16* w1h  = (_Float16*)(ws + OFF_W1H);
    _Float16* whh  = (_Float16*)(ws + OFF_WHH);
    float*    bsum = (float*)(ws + OFF_BS);
    u64*      hx   = (u64*)(ws + OFF_HX);
    u32*      ctl  = (u32*)(ws + OFF_CTL);
    float*    out  = (float*)d_out;

    // zero h buffers (h(0)=0 with tag 0) + ctl (claims, done); ws is poisoned
    (void)hipMemsetAsync(ws + OFF_HX, 0, ZERO_SIZE, stream);

    prep_kernel<<<2048, 256, 0, stream>>>(xs, wih0, whh0, b0, wih1, whh1, b1,
                                          x0h, w0h, w1h, whh, bsum);

    // layer 0
    gemm_kernel<<<dim3(256, 8, 2), 256, 0, stream>>>(x0h, w0h, bsum, pre, 256);
    rnn_kernel<<<256, 256, 0, stream>>>(pre, whh, hx, ctl, xh1, out, 0);

    // layer 1
    gemm_kernel<<<dim3(256, 8, 2), 256, 0, stream>>>(xh1, w1h, bsum + 1024, pre, 1024);
    rnn_kernel<<<256, 256, 0, stream>>>(pre, whh + 2 * 512 * 512,
                                        hx + HX_LAYER_STRIDE, ctl + 32,
                                        xh1, out, 1);
}

// Round 10
// 2708.981 us; speedup vs baseline: 1.3155x; 1.3155x over previous
//
#include <hip/hip_runtime.h>
#include <hip/hip_fp16.h>

// ---------------------------------------------------------------------------
// 2-layer bidirectional tanh RNN, B=32, T=512, E=256, H=512.
//   prep:  fp32->fp16 conversions (+ xs transpose, bias sums)
//   gemm:  pre[d][t*32+b][j] = X @ W_ih[d]^T + bias   (fp16 MFMA)
//   rnn:   512 sequential steps; 16 worker blocks/dir, each owns a 32-wide
//          j-slice of W_hh in VGPRs.  TAGGED u64 exchange (tag<<32 | 2xfp16),
//          spin-gather until tags match.
//
// ROUND 9 (resubmitted unchanged after container failure) — clean A/B on the
// ONLY untested isolated variable: the coherence point, holding the
// proven-best R1 body byte-identical.
//   Ledger (us/step): R1 tagged+SYSTEM 2.70 | R3 flags+agent 2.89 |
//   R4 +staging 3.21 | R6 direct-gather 8.46 | R7 8-blk 3.07 | R8 drainless
//   +heaters 3.57.  R1 is unbeaten; every redesign offset its own gains.
//   R1's 296MB FETCH_SIZE shows its sc1 poll rounds were true HBM/fabric
//   round-trips (~900cy).  This round: R1 body EXACTLY, but hx atomics at
//   AGENT scope (sc0: served by the XCD's L2, ~300cy) + the R3/R7/R8-proven
//   XCD-claiming prologue so each direction's 16 workers share one L2
//   (agent scope is only same-XCD coherent — the round-4 lesson).
//   No flags, no staging, no heaters, no barrier surgery: one variable.
// ---------------------------------------------------------------------------

#define T_ 512
#define B_ 32
#define E_ 256
#define H_ 512

using half8 = _Float16 __attribute__((ext_vector_type(8)));
using f32x4 = float __attribute__((ext_vector_type(4)));
typedef unsigned long long u64;
typedef unsigned int u32;

// workspace layout (bytes)
static constexpr size_t OFF_PRE   = 0;                         // f16 [2][16384][512]  32 MB
static constexpr size_t OFF_XH1   = 32ull << 20;               // f16 [16384][1024]    32 MB
static constexpr size_t OFF_X0H   = 64ull << 20;               // f16 [16384][256]      8 MB
static constexpr size_t OFF_W0H   = 72ull << 20;               // f16 [2][512][256]   0.5 MB
static constexpr size_t OFF_W1H   = OFF_W0H + (512ull << 10);  // f16 [2][512][1024]    2 MB
static constexpr size_t OFF_WHH   = OFF_W1H + (2ull << 20);    // f16 [2][2][512][512]  2 MB
static constexpr size_t OFF_BS    = OFF_WHH + (2ull << 20);    // f32 [2][2][512]       8 KB
static constexpr size_t OFF_HX    = OFF_BS + (8ull << 10);     // u64 [2 lay][2 dir][2 ph][32][256] 512 KB
static constexpr size_t OFF_CTL   = OFF_HX + (512ull << 10);   // u32 [2 lay][32]  256 B
static constexpr size_t ZERO_SIZE = (512ull << 10) + 1024;     // hx + ctl

// u64 element strides inside hx
static constexpr size_t HX_LAYER_STRIDE = 2 * 2 * 32 * 256;    // 32768 u64 per layer
static constexpr size_t HX_DIR_STRIDE   = 2 * 32 * 256;        // 16384 u64 per dir

__device__ __forceinline__ float fast_tanh(float x) {
    // tanh(x) = (e^2x - 1)/(e^2x + 1), clamped so e^2x can't overflow.
    float cx = fminf(fmaxf(x, -9.0f), 9.0f);
    float e2 = __expf(2.0f * cx);
    return (e2 - 1.0f) * __builtin_amdgcn_rcpf(e2 + 1.0f);
}

// ---------------------------------------------------------------------------
__global__ void prep_kernel(const float* __restrict__ xs,
                            const float* __restrict__ wih0,
                            const float* __restrict__ whh0,
                            const float* __restrict__ b0,
                            const float* __restrict__ wih1,
                            const float* __restrict__ whh1,
                            const float* __restrict__ b1,
                            _Float16* __restrict__ x0h,
                            _Float16* __restrict__ w0h,
                            _Float16* __restrict__ w1h,
                            _Float16* __restrict__ whh,
                            float* __restrict__ bsum)
{
    const int N0 = T_ * B_ * E_;
    const int N1 = 2 * H_ * E_;
    const int N2 = 2 * H_ * 2*H_;
    const int N3 = 2 * H_ * H_;
    const int total = N0 + N1 + N2 + 2 * N3 + 2048;
    for (int idx = blockIdx.x * blockDim.x + threadIdx.x; idx < total;
         idx += gridDim.x * blockDim.x) {
        int i = idx;
        if (i < N0) {
            int t = i >> 13;
            int r = i & 8191;
            int b = r >> 8;
            int e = r & 255;
            x0h[i] = (_Float16)xs[((size_t)(b << 9) + t) * 256 + e];
        } else if ((i -= N0) < N1) {
            w0h[i] = (_Float16)wih0[i];
        } else if ((i -= N1) < N2) {
            w1h[i] = (_Float16)wih1[i];
        } else if ((i -= N2) < N3) {
            whh[i] = (_Float16)whh0[i];
        } else if ((i -= N3) < N3) {
            whh[N3 + i] = (_Float16)whh1[i];
        } else {
            i -= N3;               // 0..2047: [layer][dir][512]
            int layer = i >> 10;
            int r = i & 1023;
            int d = r >> 9;
            int j = r & 511;
            const float* bb = layer ? b1 : b0;
            bsum[i] = bb[d * 1024 + j] + bb[d * 1024 + 512 + j];
        }
    }
}

// ---------------------------------------------------------------------------
__global__ __launch_bounds__(256, 2)
void gemm_kernel(const _Float16* __restrict__ X,
                 const _Float16* __restrict__ W,
                 const float* __restrict__ bias,
                 _Float16* __restrict__ out, int K)
{
    __shared__ _Float16 Ash[64][72];
    __shared__ _Float16 Bsh[64][72];
    const int m0 = blockIdx.x * 64, n0 = blockIdx.y * 64, d = blockIdx.z;
    const _Float16* Wd = W + (size_t)d * 512 * K;
    const int tid = threadIdx.x;
    const int l = tid & 63, w = tid >> 6;
    const int wm = w & 1, wn = w >> 1;
    const int lm = l & 15, q = l >> 4;
    f32x4 c[2][2] = {};
    for (int kk = 0; kk < K; kk += 64) {
        for (int ci = tid; ci < 512; ci += 256) {
            int row = ci >> 3, col = (ci & 7) * 8;
            *(half8*)&Ash[row][col] =
                *(const half8*)&X[(size_t)(m0 + row) * K + kk + col];
            *(half8*)&Bsh[row][col] =
                *(const half8*)&Wd[(size_t)(n0 + row) * K + kk + col];
        }
        __syncthreads();
        for (int kt = 0; kt < 2; ++kt) {
            const int kof = kt * 32 + q * 8;
            half8 a0 = *(const half8*)&Ash[wm * 32 + lm][kof];
            half8 a1 = *(const half8*)&Ash[wm * 32 + 16 + lm][kof];
            half8 b0f = *(const half8*)&Bsh[wn * 32 + lm][kof];
            half8 b1f = *(const half8*)&Bsh[wn * 32 + 16 + lm][kof];
            c[0][0] = __builtin_amdgcn_mfma_f32_16x16x32_f16(a0, b0f, c[0][0], 0, 0, 0);
            c[0][1] = __builtin_amdgcn_mfma_f32_16x16x32_f16(a0, b1f, c[0][1], 0, 0, 0);
            c[1][0] = __builtin_amdgcn_mfma_f32_16x16x32_f16(a1, b0f, c[1][0], 0, 0, 0);
            c[1][1] = __builtin_amdgcn_mfma_f32_16x16x32_f16(a1, b1f, c[1][1], 0, 0, 0);
        }
        __syncthreads();
    }
    _Float16* outd = out + (size_t)d * 16384 * 512;
    for (int mi = 0; mi < 2; ++mi)
        for (int ni = 0; ni < 2; ++ni) {
            int col = n0 + wn * 32 + ni * 16 + lm;
            float bv = bias[d * 512 + col];
            for (int r = 0; r < 4; ++r) {
                int rowm = m0 + wm * 32 + mi * 16 + q * 4 + r;
                outd[(size_t)rowm * 512 + col] = (_Float16)(c[mi][ni][r] + bv);
            }
        }
}

// ---------------------------------------------------------------------------
// hx per dir: [2 phase][32 b][256 jp] u64; word = (tag<<32)|(f16 j=2jp+1)<<16|(f16 j=2jp)
// h(s) lives in phase s&1 with tag s.  Block = 256 threads, 4 waves:
//   wave wv: wm = wv&1 (m-tile of b), wn = wv>>1 (16-col n-frag).
// Reader: 32 fully-coalesced u64 AGENT-scope loads (lane tid -> [b=i][jp=tid]),
// wave-uniform batched tag-spin, then LDS scatter to A-frag layout.
// ctl per layer (u32[32]): [0..7] per-XCD claim counters, [8] rolecnt,
//                          [16..23] xcdrole (0 unset, 1 dir0, 2 dir1, 3 none)
__global__ __launch_bounds__(256)
void rnn_kernel(const _Float16* __restrict__ pre,   // [2][16384][512] f16
                const _Float16* __restrict__ whh,   // this layer: [2][512][512] f16
                u64* __restrict__ hx,               // this layer: [2 dir][2 ph][32][256] u64
                u32* __restrict__ ctl,              // this layer: [32] u32
                _Float16* __restrict__ xh1,         // layer0 out: [16384][1024] f16
                float* __restrict__ dout,           // final output buffer
                int layer)
{
    __shared__ uint4 As[64 * 33];                   // A-frag staging, 33.8 KB
    __shared__ int sh_role, sh_slot;

    const int tid = threadIdx.x;

    // ---- XCD-aware worker claiming (tid 0 only, broadcast via LDS).
    //      First two XCDs to collect 16 blocks become dir-0 / dir-1 (role
    //      claimed by the 16th block => groups always complete => no
    //      deadlock; 256 blocks / 8 XCDs => every XCD reaches 32). ----
    if (tid == 0) {
        int xcc;
        asm volatile("s_getreg_b32 %0, hwreg(HW_REG_XCC_ID)" : "=s"(xcc));
        xcc &= 7;
        u32 slot = __hip_atomic_fetch_add(&ctl[xcc], 1u, __ATOMIC_RELAXED,
                                          __HIP_MEMORY_SCOPE_SYSTEM);
        int role = 0;
        if (slot < 16u) {
            if (slot == 15u) {
                u32 r = __hip_atomic_fetch_add(&ctl[8], 1u, __ATOMIC_ACQ_REL,
                                               __HIP_MEMORY_SCOPE_SYSTEM);
                role = (r < 2u) ? (int)r + 1 : 3;
                __hip_atomic_store(&ctl[16 + xcc], (u32)role, __ATOMIC_RELEASE,
                                   __HIP_MEMORY_SCOPE_SYSTEM);
            } else {
                long it = 0;
                while (true) {
                    u32 r = __hip_atomic_load(&ctl[16 + xcc], __ATOMIC_ACQUIRE,
                                              __HIP_MEMORY_SCOPE_SYSTEM);
                    if (r) { role = (int)r; break; }
                    if (++it > 100000000) { role = 3; break; }   // paranoia escape
                }
            }
        }
        sh_role = role;
        sh_slot = (int)slot;
    }
    __syncthreads();
    const int role = sh_role;
    const int g = sh_slot;                          // worker id within direction
    if (role == 0 || role == 3) return;             // surplus block: exit
    const int d = role - 1;

    const int wv = tid >> 6, l = tid & 63;
    const int lm = l & 15, q = l >> 4;
    const int wm = wv & 1, wn = wv >> 1;
    const int jn = g * 32 + wn * 16;                // this wave's 16-col slice
    const int bA = wm * 16 + lm;                    // A-frag row (b)
    const int bq = wm * 16 + q * 4;                 // C/D row base (b)

    // Preload W B-fragments: lane holds W[j = jn+lm][k = kt*32 + q*8 + e]
    half8 Bf[16];
    {
        const _Float16* wrow = whh + ((size_t)d * 512 + jn + lm) * 512;
#pragma unroll
        for (int kt = 0; kt < 16; ++kt)
            Bf[kt] = *(const half8*)&wrow[kt * 32 + q * 8];
    }

    u64* hbd = hx + (size_t)d * HX_DIR_STRIDE;
    const int jp_pub = (jn + (lm & ~1)) >> 1;       // word this lane-pair publishes
    const int scat_base = ((tid >> 2) * 33) * 4 + (tid & 3);  // LDS dword idx base (b=0)
    u32* AsW = (u32*)As;

    for (int s = 0; s < T_; ++s) {
        const int t = d ? (T_ - 1 - s) : s;

        // ---- issue pre loads early (latency hides under the spin) ----
        const _Float16* prow = pre + ((size_t)d * 16384 + (size_t)t * B_) * 512 + jn + lm;
        _Float16 pv[4];
#pragma unroll
        for (int r = 0; r < 4; ++r)
            pv[r] = prow[(size_t)(bq + r) * 512];

        // ---- coalesced tagged gather of full h(s): lane tid <- [b=i][jp=tid]
        //      AGENT scope => sc0 => bypass L1, served by this XCD's L2. ----
        const u64* src = hbd + (size_t)(s & 1) * 8192 + tid;
        const unsigned tag = (unsigned)s;
        u64 wvv[32];
        {
            bool stale = true;
            long it = 0;
            do {
#pragma unroll
                for (int i = 0; i < 32; ++i)
                    wvv[i] = __hip_atomic_load(&src[i * 256],
                                               __ATOMIC_RELAXED, __HIP_MEMORY_SCOPE_AGENT);
                bool ok = true;
#pragma unroll
                for (int i = 0; i < 32; ++i)
                    ok &= ((unsigned)(wvv[i] >> 32) == tag);
                stale = __any(!ok);
            } while (stale && ++it < 4000000);      // escape => wrong data, not hang
        }

        // ---- LDS scatter to A-frag layout (lane tid: kg=tid>>2, slot=tid&3) ----
        __syncthreads();   // previous step's frag reads done before overwrite
#pragma unroll
        for (int i = 0; i < 32; ++i)
            AsW[scat_base + i * 4] = (u32)wvv[i];
        __syncthreads();

        // ---- A-fragments + MFMA (two accumulators to halve dep chain) ----
        f32x4 c0, c1;
#pragma unroll
        for (int r = 0; r < 4; ++r) { c0[r] = (float)pv[r]; c1[r] = 0.0f; }
#pragma unroll
        for (int kt = 0; kt < 16; ++kt) {
            union { uint4 u; half8 h; } cv;
            cv.u = As[(kt * 4 + q) * 33 + bA];
            if (kt & 1) c1 = __builtin_amdgcn_mfma_f32_16x16x32_f16(cv.h, Bf[kt], c1, 0, 0, 0);
            else        c0 = __builtin_amdgcn_mfma_f32_16x16x32_f16(cv.h, Bf[kt], c0, 0, 0, 0);
        }

        // ---- tanh + publish + outputs ----
        u64* dst = hbd + (size_t)((s + 1) & 1) * 8192;
        const u64 tagw = ((u64)(unsigned)(s + 1)) << 32;
        const int j = jn + lm;
        float hv[4];
        unsigned hb[4];
#pragma unroll
        for (int r = 0; r < 4; ++r) {
            hv[r] = fast_tanh(c0[r] + c1[r]);
            union { _Float16 f; unsigned short u; } cb;
            cb.f = (_Float16)hv[r];
            hb[r] = cb.u;
        }
#pragma unroll
        for (int r = 0; r < 4; ++r) {
            unsigned p = __shfl_xor(hb[r], 1, 64);
            unsigned lo = (l & 1) ? p : hb[r];
            unsigned hi = (l & 1) ? hb[r] : p;
            if ((r >> 1) == (l & 1)) {   // even lane stores r=0,1; odd r=2,3
                u64 word = tagw | ((u64)hi << 16) | lo;
                __hip_atomic_store(&dst[(size_t)(bq + r) * 256 + jp_pub], word,
                                   __ATOMIC_RELAXED, __HIP_MEMORY_SCOPE_AGENT);
            }
        }
#pragma unroll
        for (int r = 0; r < 4; ++r) {
            const int b = bq + r;
            if (layer == 0) {
                xh1[((size_t)t * B_ + b) * 1024 + d * 512 + j] = (_Float16)hv[r];
            } else {
                dout[((size_t)b * T_ + t) * 1024 + d * 512 + j] = hv[r];
            }
            if (s == T_ - 1) {
                dout[16777216ull + ((size_t)(layer * 2 + d) * B_ + b) * 512 + j] = hv[r];
            }
        }
    }
}

// ---------------------------------------------------------------------------
extern "C" void kernel_launch(void* const* d_in, const int* in_sizes, int n_in,
                              void* d_out, int out_size, void* d_ws, size_t ws_size,
                              hipStream_t stream)
{
    const float* xs   = (const float*)d_in[0];
    const float* wih0 = (const float*)d_in[1];
    const float* whh0 = (const float*)d_in[2];
    const float* b0   = (const float*)d_in[3];
    const float* wih1 = (const float*)d_in[4];
    const float* whh1 = (const float*)d_in[5];
    const float* b1   = (const float*)d_in[6];

    char* ws = (char*)d_ws;
    _Float16* pre  = (_Float16*)(ws + OFF_PRE);
    _Float16* xh1  = (_Float16*)(ws + OFF_XH1);
    _Float16* x0h  = (_Float16*)(ws + OFF_X0H);
    _Float16* w0h  = (_Float16*)(ws + OFF_W0H);
    _Float16* w1h  = (_Float16*)(ws + OFF_W1H);
    _Float16* whh  = (_Float16*)(ws + OFF_WHH);
    float*    bsum = (float*)(ws + OFF_BS);
    u64*      hx   = (u64*)(ws + OFF_HX);
    u32*      ctl  = (u32*)(ws + OFF_CTL);
    float*    out  = (float*)d_out;

    // zero h buffers (h(0)=0 with tag 0) + claim counters; ws is poisoned 0xAA
    (void)hipMemsetAsync(ws + OFF_HX, 0, ZERO_SIZE, stream);

    prep_kernel<<<2048, 256, 0, stream>>>(xs, wih0, whh0, b0, wih1, whh1, b1,
                                          x0h, w0h, w1h, whh, bsum);

    // layer 0
    gemm_kernel<<<dim3(256, 8, 2), 256, 0, stream>>>(x0h, w0h, bsum, pre, 256);
    rnn_kernel<<<256, 256, 0, stream>>>(pre, whh, hx, ctl, xh1, out, 0);

    // layer 1
    gemm_kernel<<<dim3(256, 8, 2), 256, 0, stream>>>(xh1, w1h, bsum + 1024, pre, 1024);
    rnn_kernel<<<256, 256, 0, stream>>>(pre, whh + 2 * 512 * 512,
                                        hx + HX_LAYER_STRIDE, ctl + 32,
                                        xh1, out, 1);
}